// Round 6
// baseline (1297.648 us; speedup 1.0000x reference)
//
#include <hip/hip_runtime.h>
#include <hip/hip_cooperative_groups.h>
#include <cstddef>
#include <cstdint>

namespace cg = cooperative_groups;

#define C 256
#define N1_ 50000
#define N2_ 12500
#define TM 128
#define TN 128
#define LDK 40

typedef __attribute__((ext_vector_type(8))) short short8;
typedef __attribute__((ext_vector_type(4))) float f32x4;

__device__ __forceinline__ ushort f2bf(float f) {
    uint32_t u = __float_as_uint(f);
    u += 0x7FFF + ((u >> 16) & 1);   // round-to-nearest-even
    return (ushort)(u >> 16);
}
__device__ __forceinline__ float bf2f(ushort u) {
    return __uint_as_float(((uint32_t)u) << 16);
}
__device__ __forceinline__ uint2 pack4(float a, float b, float c, float d) {
    uint2 o;
    o.x = (uint32_t)f2bf(a) | ((uint32_t)f2bf(b) << 16);
    o.y = (uint32_t)f2bf(c) | ((uint32_t)f2bf(d) << 16);
    return o;
}
__device__ __forceinline__ void acc8(uint4 v, float* a) {
    a[0] += bf2f((ushort)(v.x & 0xffff)); a[1] += bf2f((ushort)(v.x >> 16));
    a[2] += bf2f((ushort)(v.y & 0xffff)); a[3] += bf2f((ushort)(v.y >> 16));
    a[4] += bf2f((ushort)(v.z & 0xffff)); a[5] += bf2f((ushort)(v.z >> 16));
    a[6] += bf2f((ushort)(v.w & 0xffff)); a[7] += bf2f((ushort)(v.w >> 16));
}

struct MegaParams {
    const float4* x4; int nx4;
    uint2* xbf;
    const float4* wl0f; const float4* wr0f;
    uint2* wl0b2; uint2* wr0b2;
    const int* e0s; const int* e0d; int E0;
    const int* e1s; const int* e1d; int E1;
    int* cnt0; int* cnt1;
    int* off0; int* off1;
    int* bsum0; int* bbase0; int* bsum1; int* bbase1;
    int* esrc0; int* esrc1;
    const ushort* xbf_u;
    ushort* aggr0; ushort* h0raw; ushort* aggr1; ushort* h1raw;
    const ushort* wl0b; const ushort* wr0b;
    ushort* wl1b; ushort* wr1b;
    const float* bl0; const float* ga0; const float* be0;
    const float* Wl1f; const float* Wr1f; const float* bl1;
    float* bias1;
    const float* ga1; const float* be1;
    float* colsum0; float* colsq0; float* colsum1; float* colsq1;
    float4* out;
};

union alignas(16) Smem {
    int scan[256];
    struct { ushort As[TM * LDK]; ushort Bs[TN * LDK]; float csum[TN]; float csq[TN]; } g;
    struct { float ss[C]; float st[C]; float red[256]; } fx;
    struct { float mu[C]; float rs[C]; } nm;
};

__device__ __forceinline__ int block_incl_scan(int v, int* buf) {
    const int t = threadIdx.x;
    buf[t] = v;
    __syncthreads();
    for (int d = 1; d < 256; d <<= 1) {
        int o = (t >= d) ? buf[t - d] : 0;
        __syncthreads();
        buf[t] += o;
        __syncthreads();
    }
    return buf[t];   // inclusive
}

// ---- one 128x128 GEMM tile: h = relu([Aagg|Axt] @ [Wl;Wr]^T + bias), bf16 out + col stats ----
__device__ void gemm_tile(int tile, const ushort* __restrict__ Aagg, const ushort* __restrict__ Axt,
                          const ushort* __restrict__ Wl, const ushort* __restrict__ Wr,
                          const float* __restrict__ bias, ushort* __restrict__ h,
                          float* __restrict__ colsum, float* __restrict__ colsq,
                          int M, Smem& sm) {
    const int tid = threadIdx.x;
    const int n0 = (tile & 1) * TN;
    const int m0 = (tile >> 1) * TM;
    const int wid = tid >> 6, lane = tid & 63;
    const int l15 = lane & 15, quad = lane >> 4;
    const int wm = (wid & 1) * 64, wn = (wid >> 1) * 64;
    const int srow = tid >> 2;
    const int skoff = (tid & 3) * 8;

    if (tid < TN) { sm.g.csum[tid] = 0.f; sm.g.csq[tid] = 0.f; }

    f32x4 acc[4][4];
#pragma unroll
    for (int i = 0; i < 4; ++i)
#pragma unroll
        for (int j = 0; j < 4; ++j) acc[i][j] = (f32x4){0.f, 0.f, 0.f, 0.f};

#pragma unroll 1
    for (int kt = 0; kt < 16; ++kt) {
        const int ks = kt * 32;
        const ushort* Ab = (ks < 256) ? Aagg : Axt;
        const ushort* Bb = (ks < 256) ? Wl : Wr;
        const int k0 = ks & 255;
        int r0 = min(m0 + srow, M - 1);
        int r1 = min(m0 + srow + 64, M - 1);
        uint4 a0 = *(const uint4*)&Ab[(size_t)r0 * C + k0 + skoff];
        uint4 a1 = *(const uint4*)&Ab[(size_t)r1 * C + k0 + skoff];
        uint4 b0 = *(const uint4*)&Bb[(size_t)(n0 + srow) * C + k0 + skoff];
        uint4 b1 = *(const uint4*)&Bb[(size_t)(n0 + srow + 64) * C + k0 + skoff];
        __syncthreads();
        *(uint4*)&sm.g.As[srow * LDK + skoff] = a0;
        *(uint4*)&sm.g.As[(srow + 64) * LDK + skoff] = a1;
        *(uint4*)&sm.g.Bs[srow * LDK + skoff] = b0;
        *(uint4*)&sm.g.Bs[(srow + 64) * LDK + skoff] = b1;
        __syncthreads();

        short8 af[4], bw[4];
#pragma unroll
        for (int mi = 0; mi < 4; ++mi)
            af[mi] = *(const short8*)&sm.g.As[(wm + mi * 16 + l15) * LDK + quad * 8];
#pragma unroll
        for (int ni = 0; ni < 4; ++ni)
            bw[ni] = *(const short8*)&sm.g.Bs[(wn + ni * 16 + l15) * LDK + quad * 8];
#pragma unroll
        for (int mi = 0; mi < 4; ++mi)
#pragma unroll
            for (int ni = 0; ni < 4; ++ni)
                acc[mi][ni] = __builtin_amdgcn_mfma_f32_16x16x32_bf16(
                    af[mi], bw[ni], acc[mi][ni], 0, 0, 0);
    }

    float lsum[4] = {0.f, 0.f, 0.f, 0.f};
    float lsq[4]  = {0.f, 0.f, 0.f, 0.f};
#pragma unroll
    for (int ni = 0; ni < 4; ++ni) {
        const int col = wn + ni * 16 + l15;
        const float bv = bias[n0 + col];
#pragma unroll
        for (int mi = 0; mi < 4; ++mi) {
#pragma unroll
            for (int r = 0; r < 4; ++r) {
                int m = m0 + wm + mi * 16 + quad * 4 + r;
                float v = acc[mi][ni][r] + bv;
                v = fmaxf(v, 0.f);
                if (m < M) {
                    h[(size_t)m * C + n0 + col] = f2bf(v);
                    lsum[ni] += v;
                    lsq[ni] += v * v;
                }
            }
        }
    }
#pragma unroll
    for (int ni = 0; ni < 4; ++ni) {
        const int col = wn + ni * 16 + l15;
        atomicAdd(&sm.g.csum[col], lsum[ni]);
        atomicAdd(&sm.g.csq[col], lsq[ni]);
    }
    __syncthreads();
    if (tid < TN) {
        atomicAdd(&colsum[n0 + tid], sm.g.csum[tid]);
        atomicAdd(&colsq[n0 + tid], sm.g.csq[tid]);
    }
}

// ---- mean aggregation phase: one wave per target, grid-stride ----
__device__ void aggregate_phase(const uint4* __restrict__ xb4, const int* __restrict__ esrc,
                                const int* __restrict__ off, uint4* __restrict__ out4,
                                int n_tgt, int nwaves) {
    const int tid = threadIdx.x;
    const int lane = tid & 63;
    const int half = lane >> 5, l31 = lane & 31;
    const int gw = blockIdx.x * 4 + (tid >> 6);
    for (int t = gw; t < n_tgt; t += nwaves) {
        const int base = off[t];
        const int deg = off[t + 1] - base;
        float a[8] = {0.f, 0.f, 0.f, 0.f, 0.f, 0.f, 0.f, 0.f};
        int i = 0;
        for (; i + 8 <= deg; i += 8) {
            int s0 = esrc[base + i + half];
            int s1 = esrc[base + i + 2 + half];
            int s2 = esrc[base + i + 4 + half];
            int s3 = esrc[base + i + 6 + half];
            uint4 v0 = xb4[(size_t)s0 * 32 + l31];
            uint4 v1 = xb4[(size_t)s1 * 32 + l31];
            uint4 v2 = xb4[(size_t)s2 * 32 + l31];
            uint4 v3 = xb4[(size_t)s3 * 32 + l31];
            acc8(v0, a); acc8(v1, a); acc8(v2, a); acc8(v3, a);
        }
        for (; i + 2 <= deg; i += 2) {
            int s = esrc[base + i + half];
            uint4 v = xb4[(size_t)s * 32 + l31];
            acc8(v, a);
        }
        if ((deg & 1) && half == 0) {
            int s = esrc[base + deg - 1];
            uint4 v = xb4[(size_t)s * 32 + l31];
            acc8(v, a);
        }
#pragma unroll
        for (int j = 0; j < 8; ++j) a[j] += __shfl_xor(a[j], 32, 64);
        if (half == 0) {
            float inv = 1.0f / (float)(deg > 1 ? deg : 1);
            uint4 o;
            o.x = (uint32_t)f2bf(a[0] * inv) | ((uint32_t)f2bf(a[1] * inv) << 16);
            o.y = (uint32_t)f2bf(a[2] * inv) | ((uint32_t)f2bf(a[3] * inv) << 16);
            o.z = (uint32_t)f2bf(a[4] * inv) | ((uint32_t)f2bf(a[5] * inv) << 16);
            o.w = (uint32_t)f2bf(a[6] * inv) | ((uint32_t)f2bf(a[7] * inv) << 16);
            out4[(size_t)t * 32 + l31] = o;
        }
    }
}

__global__ __launch_bounds__(256, 2) void mega_kernel(MegaParams p) {
    cg::grid_group grid = cg::this_grid();
    __shared__ Smem sm;
    const int tid = threadIdx.x;
    const int nblk = gridDim.x;
    const int gtid = blockIdx.x * 256 + tid;
    const int gsz = nblk * 256;
    const int nwaves = nblk * 4;

    // ---------- Phase A: cast x + cast W0 (bf16) ; hist0 ; hist1 ----------
    {
        const int nw4 = C * C / 4;
        const int total = p.nx4 + 2 * nw4;
        for (int i = gtid; i < total; i += gsz) {
            if (i < p.nx4) {
                float4 v = p.x4[i];
                p.xbf[i] = pack4(v.x, v.y, v.z, v.w);
            } else if (i < p.nx4 + nw4) {
                int j = i - p.nx4;
                float4 v = p.wl0f[j];
                p.wl0b2[j] = pack4(v.x, v.y, v.z, v.w);
            } else {
                int j = i - p.nx4 - nw4;
                float4 v = p.wr0f[j];
                p.wr0b2[j] = pack4(v.x, v.y, v.z, v.w);
            }
        }
        for (int i = gtid; i < p.E0; i += gsz) atomicAdd(&p.cnt0[p.e0d[i]], 1);
        for (int i = gtid; i < p.E1; i += gsz) atomicAdd(&p.cnt1[p.e1d[i]], 1);
    }
    __threadfence(); grid.sync();

    // ---------- Phase C1: per-block chunk sums ----------
    const int ch0 = (N1_ + nblk - 1) / nblk;   // <=196 for nblk>=256
    const int ch1 = (N2_ + nblk - 1) / nblk;
    {
        int i0 = blockIdx.x * ch0 + tid;
        int v0 = (tid < ch0 && i0 < N1_) ? p.cnt0[i0] : 0;
        int incl0 = block_incl_scan(v0, sm.scan);
        if (tid == 255) p.bsum0[blockIdx.x] = incl0;
        __syncthreads();
        int i1 = blockIdx.x * ch1 + tid;
        int v1 = (tid < ch1 && i1 < N2_) ? p.cnt1[i1] : 0;
        int incl1 = block_incl_scan(v1, sm.scan);
        if (tid == 255) p.bsum1[blockIdx.x] = incl1;
    }
    __threadfence(); grid.sync();

    // ---------- Phase C2: scan the block sums (block 0: layer0, block 1: layer1) ----------
    if (blockIdx.x < 2) {
        const int* bs = blockIdx.x ? p.bsum1 : p.bsum0;
        int* bb = blockIdx.x ? p.bbase1 : p.bbase0;
        int a0 = (2 * tid < nblk) ? bs[2 * tid] : 0;
        int a1 = (2 * tid + 1 < nblk) ? bs[2 * tid + 1] : 0;
        int s = a0 + a1;
        int incl = block_incl_scan(s, sm.scan);
        int excl = incl - s;
        if (2 * tid < nblk) bb[2 * tid] = excl;
        if (2 * tid + 1 < nblk) bb[2 * tid + 1] = excl + a0;
        if (tid == 255) {
            if (blockIdx.x) p.off1[N2_] = incl;
            else p.off0[N1_] = incl;
        }
    }
    __threadfence(); grid.sync();

    // ---------- Phase C3: chunk exclusive scans -> CSR offsets ----------
    {
        int i0 = blockIdx.x * ch0 + tid;
        int v0 = (tid < ch0 && i0 < N1_) ? p.cnt0[i0] : 0;
        int incl0 = block_incl_scan(v0, sm.scan);
        if (tid < ch0 && i0 < N1_) p.off0[i0] = p.bbase0[blockIdx.x] + incl0 - v0;
        __syncthreads();
        int i1 = blockIdx.x * ch1 + tid;
        int v1 = (tid < ch1 && i1 < N2_) ? p.cnt1[i1] : 0;
        int incl1 = block_incl_scan(v1, sm.scan);
        if (tid < ch1 && i1 < N2_) p.off1[i1] = p.bbase1[blockIdx.x] + incl1 - v1;
    }
    __threadfence(); grid.sync();

    // ---------- Phase D: scatter (cnt as decrementing cursor) ----------
    {
        for (int e = gtid; e < p.E0; e += gsz) {
            int d = p.e0d[e];
            int old = atomicSub(&p.cnt0[d], 1);
            p.esrc0[p.off0[d] + old - 1] = p.e0s[e];
        }
        for (int e = gtid; e < p.E1; e += gsz) {
            int d = p.e1d[e];
            int old = atomicSub(&p.cnt1[d], 1);
            p.esrc1[p.off1[d] + old - 1] = p.e1s[e];
        }
    }
    __threadfence(); grid.sync();

    // ---------- Phase E: aggregate layer 0 ----------
    aggregate_phase((const uint4*)p.xbf_u, p.esrc0, p.off0, (uint4*)p.aggr0, N1_, nwaves);
    __threadfence(); grid.sync();

    // ---------- Phase F: gemm0 + stats ----------
    {
        const int ntiles = ((N1_ + TM - 1) / TM) * 2;   // 782
        for (int t = blockIdx.x; t < ntiles; t += nblk)
            gemm_tile(t, p.aggr0, p.xbf_u, p.wl0b, p.wr0b, p.bl0,
                      p.h0raw, p.colsum0, p.colsq0, N1_, sm);
    }
    __threadfence(); grid.sync();

    // ---------- Phase G: fixup (blocks<256) + aggregate layer 1 ----------
    if (blockIdx.x < 256) {
        const float invN = 1.0f / (float)N1_;
        float m = p.colsum0[tid] * invN;
        float v = p.colsq0[tid] * invN - m * m;
        float r = rsqrtf(fmaxf(v, 0.f) + 1e-5f);
        float s = p.ga0[tid] * r;
        sm.fx.ss[tid] = s;
        sm.fx.st[tid] = p.be0[tid] - m * s;
        __syncthreads();
        const int n = blockIdx.x;
        float wl = p.Wl1f[(size_t)n * C + tid];
        float wr = p.Wr1f[(size_t)n * C + tid];
        p.wl1b[(size_t)n * C + tid] = f2bf(wl * sm.fx.ss[tid]);
        p.wr1b[(size_t)n * C + tid] = f2bf(wr * sm.fx.ss[tid]);
        sm.fx.red[tid] = sm.fx.st[tid] * (wl + wr);
        __syncthreads();
        for (int d = 128; d > 0; d >>= 1) {
            if (tid < d) sm.fx.red[tid] += sm.fx.red[tid + d];
            __syncthreads();
        }
        if (tid == 0) p.bias1[n] = p.bl1[n] + sm.fx.red[0];
    }
    aggregate_phase((const uint4*)p.h0raw, p.esrc1, p.off1, (uint4*)p.aggr1, N2_, nwaves);
    __threadfence(); grid.sync();

    // ---------- Phase H: gemm1 + stats ----------
    {
        const int ntiles = ((N2_ + TM - 1) / TM) * 2;   // 196
        for (int t = blockIdx.x; t < ntiles; t += nblk)
            gemm_tile(t, p.aggr1, p.h0raw, p.wl1b, p.wr1b, p.bias1,
                      p.h1raw, p.colsum1, p.colsq1, N2_, sm);
    }
    __threadfence(); grid.sync();

    // ---------- Phase I: norm1 -> fp32 out ----------
    {
        const float invN = 1.0f / (float)N2_;
        float m = p.colsum1[tid] * invN;
        float v = p.colsq1[tid] * invN - m * m;
        sm.nm.mu[tid] = p.ga1[tid] * rsqrtf(fmaxf(v, 0.f) + 1e-5f);  // scale
        sm.nm.rs[tid] = p.be1[tid] - m * sm.nm.mu[tid];              // shift
        __syncthreads();
        const uint2* hin = (const uint2*)p.h1raw;
        const int n4 = N2_ * C / 4;
        for (int i = gtid; i < n4; i += gsz) {
            int c = (i & 63) << 2;
            uint2 v2 = hin[i];
            float4 o;
            o.x = bf2f((ushort)(v2.x & 0xffff)) * sm.nm.mu[c + 0] + sm.nm.rs[c + 0];
            o.y = bf2f((ushort)(v2.x >> 16))    * sm.nm.mu[c + 1] + sm.nm.rs[c + 1];
            o.z = bf2f((ushort)(v2.y & 0xffff)) * sm.nm.mu[c + 2] + sm.nm.rs[c + 2];
            o.w = bf2f((ushort)(v2.y >> 16))    * sm.nm.mu[c + 3] + sm.nm.rs[c + 3];
            p.out[i] = o;
        }
    }
}

extern "C" void kernel_launch(void* const* d_in, const int* in_sizes, int n_in,
                              void* d_out, int out_size, void* d_ws, size_t ws_size,
                              hipStream_t stream) {
    const float* x   = (const float*)d_in[0];
    const int* e0s   = (const int*)d_in[1];
    const int* e0d   = (const int*)d_in[2];
    const int* e1s   = (const int*)d_in[3];
    const int* e1d   = (const int*)d_in[4];
    const float* Wl0 = (const float*)d_in[5];
    const float* bl0 = (const float*)d_in[6];
    const float* Wr0 = (const float*)d_in[7];
    const float* ga0 = (const float*)d_in[8];
    const float* be0 = (const float*)d_in[9];
    const float* Wl1 = (const float*)d_in[10];
    const float* bl1 = (const float*)d_in[11];
    const float* Wr1 = (const float*)d_in[12];
    const float* ga1 = (const float*)d_in[13];
    const float* be1 = (const float*)d_in[14];

    const int N0 = 200000;
    const int E0 = in_sizes[1];
    const int E1 = in_sizes[3];

    char* ws = (char*)d_ws;
    size_t o = 0;
    auto alloc = [&](size_t bytes) -> char* {
        char* p = ws + o;
        o += (bytes + 255) & ~(size_t)255;
        return p;
    };

    // zeroed region: cnt0 | cnt1 | stats (single memset)
    int* cnt0 = (int*)alloc(((size_t)N1_ + N2_ + 8 * C) * sizeof(int));
    int* cnt1 = cnt0 + N1_;
    float* stats = (float*)(cnt1 + N2_);
    float* colsum0 = stats,         *colsq0 = stats + C;
    float* colsum1 = stats + 4 * C, *colsq1 = stats + 5 * C;
    const size_t zbytes = ((size_t)N1_ + N2_ + 8 * C) * sizeof(int);

    int* off0 = (int*)alloc(((size_t)N1_ + 1) * sizeof(int));
    int* off1 = (int*)alloc(((size_t)N2_ + 1) * sizeof(int));
    int* bsum0  = (int*)alloc(512 * sizeof(int));
    int* bbase0 = (int*)alloc(512 * sizeof(int));
    int* bsum1  = (int*)alloc(512 * sizeof(int));
    int* bbase1 = (int*)alloc(512 * sizeof(int));
    ushort* x_bf  = (ushort*)alloc((size_t)N0 * C * 2);
    ushort* aggr0 = (ushort*)alloc((size_t)N1_ * C * 2);
    ushort* h0raw = (ushort*)alloc((size_t)N1_ * C * 2);
    ushort* aggr1 = aggr0;                        // aggr0 dead after gemm0
    ushort* h1raw = aggr0 + (size_t)N2_ * C;
    int* esrc0 = (int*)alloc((size_t)E0 * sizeof(int));
    int* esrc1 = (int*)alloc((size_t)E1 * sizeof(int));
    ushort* wbf = (ushort*)alloc(4 * (size_t)C * C * 2);
    ushort* wl0b = wbf, *wr0b = wbf + C * C, *wl1b = wbf + 2 * C * C, *wr1b = wbf + 3 * C * C;
    float* bias1 = (float*)alloc(C * sizeof(float));

    hipMemsetAsync(cnt0, 0, zbytes, stream);

    int occ = 0;
    hipError_t oe = hipOccupancyMaxActiveBlocksPerMultiprocessor(&occ, (const void*)mega_kernel, 256, 0);
    if (oe != hipSuccess || occ < 1) occ = 1;
    int nblk = occ * 256;
    if (nblk > 512) nblk = 512;
    if (nblk < 256) nblk = 256;

    MegaParams p;
    p.x4 = (const float4*)x; p.nx4 = N0 * C / 4;
    p.xbf = (uint2*)x_bf;
    p.wl0f = (const float4*)Wl0; p.wr0f = (const float4*)Wr0;
    p.wl0b2 = (uint2*)wl0b; p.wr0b2 = (uint2*)wr0b;
    p.e0s = e0s; p.e0d = e0d; p.E0 = E0;
    p.e1s = e1s; p.e1d = e1d; p.E1 = E1;
    p.cnt0 = cnt0; p.cnt1 = cnt1;
    p.off0 = off0; p.off1 = off1;
    p.bsum0 = bsum0; p.bbase0 = bbase0; p.bsum1 = bsum1; p.bbase1 = bbase1;
    p.esrc0 = esrc0; p.esrc1 = esrc1;
    p.xbf_u = x_bf;
    p.aggr0 = aggr0; p.h0raw = h0raw; p.aggr1 = aggr1; p.h1raw = h1raw;
    p.wl0b = wl0b; p.wr0b = wr0b;
    p.wl1b = wl1b; p.wr1b = wr1b;
    p.bl0 = bl0; p.ga0 = ga0; p.be0 = be0;
    p.Wl1f = Wl1; p.Wr1f = Wr1; p.bl1 = bl1;
    p.bias1 = bias1;
    p.ga1 = ga1; p.be1 = be1;
    p.colsum0 = colsum0; p.colsq0 = colsq0; p.colsum1 = colsum1; p.colsq1 = colsq1;
    p.out = (float4*)d_out;

    void* args[] = { &p };
    hipLaunchCooperativeKernel((const void*)mega_kernel, dim3(nblk), dim3(256),
                               args, 0, stream);
}